// Round 1
// baseline (264.696 us; speedup 1.0000x reference)
//
#include <hip/hip_runtime.h>
#include <math.h>

#define Bsz 128
#define Nn  512
#define Fd  64
#define Dd  64
#define Kk  20
#define BN  (Bsz*Nn)   // 65536

__device__ __forceinline__ float wave_sum(float v){
  #pragma unroll
  for (int o = 32; o; o >>= 1) v += __shfl_xor(v, o, 64);
  return v;
}
__device__ __forceinline__ float wave_max(float v){
  #pragma unroll
  for (int o = 32; o; o >>= 1) v = fmaxf(v, __shfl_xor(v, o, 64));
  return v;
}

// ---------------- S1: normalize embed rows (cosine prep) ----------------
__global__ __launch_bounds__(256) void k_enorm(const float* __restrict__ embed,
                                               float* __restrict__ enorm){
  int row  = blockIdx.x*4 + (threadIdx.x>>6);
  int lane = threadIdx.x & 63;
  float v  = embed[row*Dd + lane];
  float ss = wave_sum(v*v);
  float nrm = sqrtf(ss) + 1e-12f;
  enorm[row*Dd + lane] = v / nrm;
}

// ---------------- S2: cosine sims + top-K indices per row ----------------
__global__ __launch_bounds__(256) void k_topk(const float* __restrict__ enorm,
                                              int* __restrict__ topk){
  __shared__ float se[Dd];
  __shared__ float sims[Nn];
  __shared__ float rv[256];
  __shared__ int   ri[256];
  int i = blockIdx.x, tid = threadIdx.x;
  if (tid < Dd) se[tid] = enorm[i*Dd + tid];
  __syncthreads();
  for (int c = tid; c < Nn; c += 256){
    const float4* er = (const float4*)(enorm + c*Dd);
    float s = 0.f;
    #pragma unroll
    for (int q = 0; q < 16; q++){
      float4 e4 = er[q];
      s += se[4*q+0]*e4.x + se[4*q+1]*e4.y + se[4*q+2]*e4.z + se[4*q+3]*e4.w;
    }
    sims[c] = s;
  }
  __syncthreads();
  for (int t = 0; t < Kk; t++){
    // local argmax over 2 entries, tie-break lower index (jax.lax.top_k)
    float bv = -INFINITY; int bi = Nn;
    #pragma unroll
    for (int rep = 0; rep < 2; rep++){
      int c = tid + rep*256;
      float v = sims[c];
      if (v > bv || (v == bv && c < bi)){ bv = v; bi = c; }
    }
    rv[tid] = bv; ri[tid] = bi;
    __syncthreads();
    for (int s = 128; s > 0; s >>= 1){
      if (tid < s){
        float ov = rv[tid+s]; int oi = ri[tid+s];
        if (ov > rv[tid] || (ov == rv[tid] && oi < ri[tid])){ rv[tid]=ov; ri[tid]=oi; }
      }
      __syncthreads();
    }
    if (tid == 0){ topk[i*Kk + t] = ri[0]; sims[ri[0]] = -INFINITY; }
    __syncthreads();
  }
}

// ---------------- S3: g = x@W_lin, per-node attention scores ----------------
__global__ __launch_bounds__(256) void k_lin(const float* __restrict__ x,
    const float* __restrict__ W, const float* __restrict__ embed,
    const float* __restrict__ att_i, const float* __restrict__ att_j,
    const float* __restrict__ aem_i, const float* __restrict__ aem_j,
    float* __restrict__ g, float* __restrict__ s_i, float* __restrict__ s_j){
  __shared__ float4 sW[Fd*16];          // 64x64 W, row-major, as float4
  __shared__ float sai[Dd], saj[Dd], semi[Dd], semj[Dd];
  int tid = threadIdx.x;
  const float4* W4 = (const float4*)W;
  for (int t = tid; t < Fd*16; t += 256) sW[t] = W4[t];
  if (tid < Dd){ sai[tid]=att_i[tid]; saj[tid]=att_j[tid]; semi[tid]=aem_i[tid]; semj[tid]=aem_j[tid]; }
  __syncthreads();

  int row = blockIdx.x*256 + tid;       // one row per thread
  const float4* xr = (const float4*)(x + row*Fd);
  float acc[Dd];
  #pragma unroll
  for (int d = 0; d < Dd; d++) acc[d] = 0.f;
  #pragma unroll
  for (int qk = 0; qk < 16; qk++){      // 4 k-values at a time (low VGPR)
    float4 x4 = xr[qk];
    float xs[4] = {x4.x, x4.y, x4.z, x4.w};
    #pragma unroll
    for (int s = 0; s < 4; s++){
      float xv = xs[s];
      int k = 4*qk + s;
      #pragma unroll
      for (int q = 0; q < 16; q++){
        float4 w = sW[k*16+q];
        acc[4*q]   += xv*w.x;
        acc[4*q+1] += xv*w.y;
        acc[4*q+2] += xv*w.z;
        acc[4*q+3] += xv*w.w;
      }
    }
  }
  int node = row & (Nn-1);
  const float4* er = (const float4*)(embed + node*Dd);
  float si = 0.f, sj = 0.f;
  #pragma unroll
  for (int q = 0; q < 16; q++){
    float4 e4 = er[q];
    si += e4.x*semi[4*q] + e4.y*semi[4*q+1] + e4.z*semi[4*q+2] + e4.w*semi[4*q+3];
    sj += e4.x*semj[4*q] + e4.y*semj[4*q+1] + e4.z*semj[4*q+2] + e4.w*semj[4*q+3];
  }
  #pragma unroll
  for (int d = 0; d < Dd; d++){ si += acc[d]*sai[d]; sj += acc[d]*saj[d]; }
  float4* gr = (float4*)(g + row*Dd);
  #pragma unroll
  for (int q = 0; q < 16; q++){
    float4 t4; t4.x=acc[4*q]; t4.y=acc[4*q+1]; t4.z=acc[4*q+2]; t4.w=acc[4*q+3];
    gr[q] = t4;
  }
  s_i[row] = si; s_j[row] = sj;
}

// ---------------- S4: per-dest softmax over incoming edges + aggregate ----------------
__global__ __launch_bounds__(256) void k_agg(const float* __restrict__ g,
    const float* __restrict__ s_i, const float* __restrict__ s_j,
    const int* __restrict__ topk, const float* __restrict__ bias,
    float* __restrict__ agg){
  int dest = blockIdx.x*4 + (threadIdx.x>>6);   // one wave per destination node
  int lane = threadIdx.x & 63;
  int b = dest >> 9;                            // / Nn
  int i = dest & (Nn-1);
  int base = b*Nn;
  float si_d = s_i[dest];
  int j = i; float lg = -INFINITY;
  if (lane < Kk){
    j = topk[i*Kk + lane];
    if (j != i){                                 // self in topk is masked (-inf)
      float v = si_d + s_j[base + j];
      lg = (v >= 0.f) ? v : 0.2f*v;              // LeakyReLU(0.2)
    }
  } else if (lane == Kk){                        // appended self loop, never masked
    float v = si_d + s_j[dest];
    lg = (v >= 0.f) ? v : 0.2f*v;
  }
  float m  = wave_max(lg);
  float ex = (lane <= Kk) ? expf(lg - m) : 0.f;  // exp(-inf - m) == 0 for masked
  float denom = wave_sum(ex);
  float rd = 1.f / denom;
  float acc = bias[lane];
  #pragma unroll
  for (int e = 0; e <= Kk; e++){
    float w = __shfl(ex, e, 64) * rd;            // wave-uniform
    int  js = __shfl(j,  e, 64);
    if (w > 0.f) acc += w * g[(base + js)*Dd + lane];
  }
  agg[dest*Dd + lane] = acc;
}

// ---------------- S5: per-channel sum/sumsq of agg ----------------
__global__ __launch_bounds__(256) void k_stats(const float* __restrict__ src,
    float* __restrict__ gsum, float* __restrict__ gsq){
  __shared__ float ssum[256], ssq[256];
  int gt = blockIdx.x*256 + threadIdx.x;
  int d = gt & 63;
  float s = 0.f, q = 0.f;
  for (int r = gt >> 6; r < BN; r += 1024){
    float v = src[r*Dd + d];
    s += v; q += v*v;
  }
  ssum[threadIdx.x] = s; ssq[threadIdx.x] = q;
  __syncthreads();
  if (threadIdx.x < 64){
    #pragma unroll
    for (int k = 1; k < 4; k++){ s += ssum[threadIdx.x + 64*k]; q += ssq[threadIdx.x + 64*k]; }
    atomicAdd(&gsum[d], s);
    atomicAdd(&gsq[d], q);
  }
}

// ---------------- S6/S8: finalize BN constants ----------------
__global__ void k_fin(const float* __restrict__ gsum, const float* __restrict__ gsq,
                      const float* __restrict__ gamma, const float* __restrict__ beta,
                      float* __restrict__ scale, float* __restrict__ shift){
  int d = threadIdx.x;   // 64 threads
  float mu  = gsum[d] * (1.f/BN);
  float var = gsq[d] * (1.f/BN) - mu*mu;
  float rstd = 1.f / sqrtf(var + 1e-5f);
  float sc = gamma[d] * rstd;
  scale[d] = sc;
  shift[d] = beta[d] - mu*sc;
}

// ---------------- S7: h2 = relu(bn1(agg)) * embed (in place) + BN2 stats ----------------
__global__ __launch_bounds__(256) void k_h2(float* __restrict__ agg,
    const float* __restrict__ embed, const float* __restrict__ scale1,
    const float* __restrict__ shift1, float* __restrict__ gsum2, float* __restrict__ gsq2){
  __shared__ float ssum[256], ssq[256];
  int gt = blockIdx.x*256 + threadIdx.x;
  int d = gt & 63;
  float sc = scale1[d], sh = shift1[d];
  int r0 = gt >> 6;
  float e = embed[(r0 & (Nn-1))*Dd + d];   // row stride 1024 keeps node constant
  float s = 0.f, q = 0.f;
  for (int r = r0; r < BN; r += 1024){
    int idx = r*Dd + d;
    float v = agg[idx]*sc + sh;
    v = fmaxf(v, 0.f);
    v *= e;
    agg[idx] = v;
    s += v; q += v*v;
  }
  ssum[threadIdx.x] = s; ssq[threadIdx.x] = q;
  __syncthreads();
  if (threadIdx.x < 64){
    #pragma unroll
    for (int k = 1; k < 4; k++){ s += ssum[threadIdx.x + 64*k]; q += ssq[threadIdx.x + 64*k]; }
    atomicAdd(&gsum2[d], s);
    atomicAdd(&gsq2[d], q);
  }
}

// ---------------- S9: bn2 + relu + Linear(D,1) head ----------------
__global__ __launch_bounds__(256) void k_out(const float* __restrict__ h2,
    const float* __restrict__ scale2, const float* __restrict__ shift2,
    const float* __restrict__ outW, const float* __restrict__ outb,
    float* __restrict__ out){
  int row  = blockIdx.x*4 + (threadIdx.x>>6);
  int lane = threadIdx.x & 63;
  float v = h2[row*Dd + lane]*scale2[lane] + shift2[lane];
  v = fmaxf(v, 0.f) * outW[lane];
  float s = wave_sum(v);
  if (lane == 0) out[row] = s + outb[0];
}

extern "C" void kernel_launch(void* const* d_in, const int* in_sizes, int n_in,
                              void* d_out, int out_size, void* d_ws, size_t ws_size,
                              hipStream_t stream){
  const float* data  = (const float*)d_in[0];
  // d_in[1] = org_edge_index — unused by the reference computation
  const float* embed = (const float*)d_in[2];
  const float* W_lin = (const float*)d_in[3];
  const float* att_i = (const float*)d_in[4];
  const float* att_j = (const float*)d_in[5];
  const float* aem_i = (const float*)d_in[6];
  const float* aem_j = (const float*)d_in[7];
  const float* bias  = (const float*)d_in[8];
  const float* g1    = (const float*)d_in[9];
  const float* b1    = (const float*)d_in[10];
  const float* g2    = (const float*)d_in[11];
  const float* b2    = (const float*)d_in[12];
  const float* outW  = (const float*)d_in[13];
  const float* outb  = (const float*)d_in[14];
  float* out = (float*)d_out;

  float* ws    = (float*)d_ws;
  float* g     = ws;                       // 4,194,304 f32  (16 MB)
  float* agg   = ws + 4194304;             // 4,194,304 f32  (16 MB, reused as h2)
  float* enorm = ws + 8388608;             // 32,768
  float* s_i   = enorm + 32768;            // 65,536
  float* s_j   = s_i + 65536;              // 65,536
  int*   topk  = (int*)(s_j + 65536);      // 10,240 int
  float* st    = (float*)(topk + Nn*Kk);   // stats block
  float* sum1 = st,      *sq1 = st+64,  *sum2 = st+128, *sq2 = st+192;
  float* sc1  = st+256,  *sh1 = st+320, *sc2  = st+384, *sh2 = st+448;

  hipMemsetAsync(st, 0, 256*sizeof(float), stream);            // zero stat accumulators
  k_enorm<<<Nn/4, 256, 0, stream>>>(embed, enorm);
  k_topk <<<Nn,   256, 0, stream>>>(enorm, topk);
  k_lin  <<<BN/256, 256, 0, stream>>>(data, W_lin, embed, att_i, att_j, aem_i, aem_j,
                                      g, s_i, s_j);
  k_agg  <<<BN/4, 256, 0, stream>>>(g, s_i, s_j, topk, bias, agg);
  k_stats<<<256,  256, 0, stream>>>(agg, sum1, sq1);
  k_fin  <<<1, 64, 0, stream>>>(sum1, sq1, g1, b1, sc1, sh1);
  k_h2   <<<256,  256, 0, stream>>>(agg, embed, sc1, sh1, sum2, sq2);
  k_fin  <<<1, 64, 0, stream>>>(sum2, sq2, g2, b2, sc2, sh2);
  k_out  <<<BN/4, 256, 0, stream>>>(agg, sc2, sh2, outW, outb, out);
}

// Round 2
// 215.324 us; speedup vs baseline: 1.2293x; 1.2293x over previous
//
#include <hip/hip_runtime.h>
#include <math.h>

#define Bsz 128
#define Nn  512
#define Fd  64
#define Dd  64
#define Kk  20
#define BN  (Bsz*Nn)   // 65536

__device__ __forceinline__ float wave_sum(float v){
  #pragma unroll
  for (int o = 32; o; o >>= 1) v += __shfl_xor(v, o, 64);
  return v;
}

// ---------------- S1: normalize embed rows (cosine prep) ----------------
__global__ __launch_bounds__(256) void k_enorm(const float* __restrict__ embed,
                                               float* __restrict__ enorm){
  int row  = blockIdx.x*4 + (threadIdx.x>>6);
  int lane = threadIdx.x & 63;
  float v  = embed[row*Dd + lane];
  float ss = wave_sum(v*v);
  float nrm = sqrtf(ss) + 1e-12f;
  enorm[row*Dd + lane] = v / nrm;
}

// ---------------- S2: cosine sims + top-K, one wave per row, regs only ----------------
__global__ __launch_bounds__(256) void k_topk(const float* __restrict__ enorm,
                                              int* __restrict__ topk){
  __shared__ float se[256];              // the block's 4 query rows
  int tid = threadIdx.x;
  se[tid] = enorm[blockIdx.x*256 + tid];
  __syncthreads();
  int wv = tid >> 6, lane = tid & 63;
  int row = blockIdx.x*4 + wv;
  const float4* sev = (const float4*)(se + wv*64);
  float av[8];                           // sims for cols lane + 64*rep
  #pragma unroll
  for (int rep = 0; rep < 8; rep++){
    int c = rep*64 + lane;
    const float4* er = (const float4*)(enorm + c*64);
    float s0 = 0.f, s1 = 0.f;
    #pragma unroll
    for (int q = 0; q < 16; q += 2){
      float4 a  = er[q],   b  = sev[q];
      float4 a2 = er[q+1], b2 = sev[q+1];
      s0 += a.x*b.x + a.y*b.y + a.z*b.z + a.w*b.w;
      s1 += a2.x*b2.x + a2.y*b2.y + a2.z*b2.z + a2.w*b2.w;
    }
    av[rep] = s0 + s1;
  }
  // 20 argmax iterations, tie-break lower index (jax.lax.top_k), no syncs
  #pragma unroll 1
  for (int t = 0; t < Kk; t++){
    float bv = av[0]; int br = 0;
    #pragma unroll
    for (int rep = 1; rep < 8; rep++)
      if (av[rep] > bv){ bv = av[rep]; br = rep; }   // strict > keeps lowest c per lane
    int ci = br*64 + lane;
    #pragma unroll
    for (int o = 32; o; o >>= 1){
      float ov = __shfl_xor(bv, o, 64);
      int   oi = __shfl_xor(ci, o, 64);
      if (ov > bv || (ov == bv && oi < ci)){ bv = ov; ci = oi; }
    }
    if (lane == 0) topk[row*Kk + t] = ci;
    int wr = ci >> 6; bool me = ((ci & 63) == lane);
    #pragma unroll
    for (int rep = 0; rep < 8; rep++)
      if (me && rep == wr) av[rep] = -INFINITY;
  }
}

// ---------------- S3: g = x@W_lin (4 rows x 4 cols / thread) + scores ----------------
__global__ __launch_bounds__(256) void k_lin(const float* __restrict__ x,
    const float* __restrict__ W, const float* __restrict__ embed,
    const float* __restrict__ att_i, const float* __restrict__ att_j,
    const float* __restrict__ aem_i, const float* __restrict__ aem_j,
    float* __restrict__ g, float* __restrict__ s_i, float* __restrict__ s_j){
  __shared__ float4 sW[Fd*16];           // 64x64 W row-major as float4 (16 KB)
  __shared__ float4 sai[16], saj[16], semi[16], semj[16];
  int tid = threadIdx.x;
  const float4* W4 = (const float4*)W;
  #pragma unroll
  for (int t = 0; t < 4; t++) sW[tid + 256*t] = W4[tid + 256*t];
  if (tid < 16){
    sai[tid]  = ((const float4*)att_i)[tid];
    saj[tid]  = ((const float4*)att_j)[tid];
    semi[tid] = ((const float4*)aem_i)[tid];
    semj[tid] = ((const float4*)aem_j)[tid];
  }
  __syncthreads();

  int rowgrp = tid >> 4, cg = tid & 15;  // 16 rowgrps x 16 colgroups
  int row0 = blockIdx.x*64 + rowgrp*4;   // 4 rows per thread
  float4 acc0 = {0,0,0,0}, acc1 = {0,0,0,0}, acc2 = {0,0,0,0}, acc3 = {0,0,0,0};
  const float4* xr0 = (const float4*)(x + (row0+0)*Fd);
  const float4* xr1 = (const float4*)(x + (row0+1)*Fd);
  const float4* xr2 = (const float4*)(x + (row0+2)*Fd);
  const float4* xr3 = (const float4*)(x + (row0+3)*Fd);
  for (int qk = 0; qk < 16; qk++){
    float4 x0 = xr0[qk], x1 = xr1[qk], x2 = xr2[qk], x3 = xr3[qk];
    float xs0[4] = {x0.x,x0.y,x0.z,x0.w};
    float xs1[4] = {x1.x,x1.y,x1.z,x1.w};
    float xs2[4] = {x2.x,x2.y,x2.z,x2.w};
    float xs3[4] = {x3.x,x3.y,x3.z,x3.w};
    #pragma unroll
    for (int s = 0; s < 4; s++){
      float4 w4 = sW[(4*qk + s)*16 + cg];
      acc0.x += xs0[s]*w4.x; acc0.y += xs0[s]*w4.y; acc0.z += xs0[s]*w4.z; acc0.w += xs0[s]*w4.w;
      acc1.x += xs1[s]*w4.x; acc1.y += xs1[s]*w4.y; acc1.z += xs1[s]*w4.z; acc1.w += xs1[s]*w4.w;
      acc2.x += xs2[s]*w4.x; acc2.y += xs2[s]*w4.y; acc2.z += xs2[s]*w4.z; acc2.w += xs2[s]*w4.w;
      acc3.x += xs3[s]*w4.x; acc3.y += xs3[s]*w4.y; acc3.z += xs3[s]*w4.z; acc3.w += xs3[s]*w4.w;
    }
  }
  float4 ai = sai[cg], aj = saj[cg], emi = semi[cg], emj = semj[cg];
  float4 av[4] = {acc0, acc1, acc2, acc3};
  #pragma unroll
  for (int r = 0; r < 4; r++){
    int row = row0 + r;
    int node = row & (Nn-1);
    float4 a4 = av[r];
    float4 e4 = ((const float4*)embed)[node*16 + cg];
    float si = a4.x*ai.x + a4.y*ai.y + a4.z*ai.z + a4.w*ai.w
             + e4.x*emi.x + e4.y*emi.y + e4.z*emi.z + e4.w*emi.w;
    float sj = a4.x*aj.x + a4.y*aj.y + a4.z*aj.z + a4.w*aj.w
             + e4.x*emj.x + e4.y*emj.y + e4.z*emj.z + e4.w*emj.w;
    #pragma unroll
    for (int o = 1; o < 16; o <<= 1){
      si += __shfl_xor(si, o, 64);
      sj += __shfl_xor(sj, o, 64);
    }
    if (cg == 0){ s_i[row] = si; s_j[row] = sj; }
    ((float4*)(g + row*Dd))[cg] = a4;
  }
}

// ---------------- S4: softmax + aggregate; XCD-swizzled, branchless gathers ----------------
__global__ __launch_bounds__(256) void k_agg(const float* __restrict__ g,
    const float* __restrict__ s_i, const float* __restrict__ s_j,
    const int* __restrict__ topk, const float* __restrict__ bias,
    float* __restrict__ agg){
  __shared__ float slg[4][24];
  __shared__ int   sid[4][24];
  // swizzle: all 128 dest-blocks of a batch land on one XCD (bid%8 preserved)
  int bid = blockIdx.x;
  int r8 = bid & 7, q = bid >> 3;
  int w128 = q & 127, t16 = q >> 7;
  int batch = t16*8 + r8;
  int wv = threadIdx.x >> 6, lane = threadIdx.x & 63;
  int dest = (batch*128 + w128)*4 + wv;
  int i = dest & (Nn-1);
  int base = batch*Nn;
  float si_d = s_i[dest];
  if (lane < Kk){
    int j = topk[i*Kk + lane];
    float lg = -INFINITY;                       // self in topk -> masked
    if (j != i){
      float v = si_d + s_j[base + j];
      lg = (v >= 0.f) ? v : 0.2f*v;             // LeakyReLU(0.2)
    }
    slg[wv][lane] = lg; sid[wv][lane] = j;
  } else if (lane < 24){
    float lg = -INFINITY; int j = i;
    if (lane == Kk){                            // appended self loop, never masked
      float v = si_d + s_j[dest];
      lg = (v >= 0.f) ? v : 0.2f*v;
    }
    slg[wv][lane] = lg; sid[wv][lane] = j;
  }
  __syncthreads();
  float la[24]; int ja[24];
  const float4* lv = (const float4*)slg[wv];
  const int4*   jv = (const int4*)sid[wv];
  #pragma unroll
  for (int qq = 0; qq < 6; qq++){
    float4 f = lv[qq]; la[4*qq]=f.x; la[4*qq+1]=f.y; la[4*qq+2]=f.z; la[4*qq+3]=f.w;
    int4  ii = jv[qq]; ja[4*qq]=ii.x; ja[4*qq+1]=ii.y; ja[4*qq+2]=ii.z; ja[4*qq+3]=ii.w;
  }
  float m = la[0];
  #pragma unroll
  for (int e = 1; e <= Kk; e++) m = fmaxf(m, la[e]);
  float ex[Kk+1]; float denom = 0.f;
  #pragma unroll
  for (int e = 0; e <= Kk; e++){ ex[e] = __expf(la[e] - m); denom += ex[e]; }
  float rd = 1.f/denom;
  float acc = bias[lane];
  #pragma unroll
  for (int e = 0; e <= Kk; e++)
    acc += (ex[e]*rd) * g[(base + ja[e])*Dd + lane];   // 21 independent gathers
  agg[dest*Dd + lane] = acc;
}

// ---------------- S5: per-channel sum/sumsq of agg ----------------
__global__ __launch_bounds__(256) void k_stats(const float* __restrict__ src,
    float* __restrict__ gsum, float* __restrict__ gsq){
  __shared__ float ssum[256], ssq[256];
  int gt = blockIdx.x*256 + threadIdx.x;
  int d = gt & 63;
  float s = 0.f, q = 0.f;
  for (int r = gt >> 6; r < BN; r += 1024){
    float v = src[r*Dd + d];
    s += v; q += v*v;
  }
  ssum[threadIdx.x] = s; ssq[threadIdx.x] = q;
  __syncthreads();
  if (threadIdx.x < 64){
    #pragma unroll
    for (int k = 1; k < 4; k++){ s += ssum[threadIdx.x + 64*k]; q += ssq[threadIdx.x + 64*k]; }
    atomicAdd(&gsum[d], s);
    atomicAdd(&gsq[d], q);
  }
}

// ---------------- S6/S8: finalize BN constants ----------------
__global__ void k_fin(const float* __restrict__ gsum, const float* __restrict__ gsq,
                      const float* __restrict__ gamma, const float* __restrict__ beta,
                      float* __restrict__ scale, float* __restrict__ shift){
  int d = threadIdx.x;   // 64 threads
  float mu  = gsum[d] * (1.f/BN);
  float var = gsq[d] * (1.f/BN) - mu*mu;
  float rstd = 1.f / sqrtf(var + 1e-5f);
  float sc = gamma[d] * rstd;
  scale[d] = sc;
  shift[d] = beta[d] - mu*sc;
}

// ---------------- S7: h2 = relu(bn1(agg)) * embed (in place) + BN2 stats ----------------
__global__ __launch_bounds__(256) void k_h2(float* __restrict__ agg,
    const float* __restrict__ embed, const float* __restrict__ scale1,
    const float* __restrict__ shift1, float* __restrict__ gsum2, float* __restrict__ gsq2){
  __shared__ float ssum[256], ssq[256];
  int gt = blockIdx.x*256 + threadIdx.x;
  int d = gt & 63;
  float sc = scale1[d], sh = shift1[d];
  int r0 = gt >> 6;
  float e = embed[(r0 & (Nn-1))*Dd + d];   // row stride 1024 keeps node constant
  float s = 0.f, q = 0.f;
  for (int r = r0; r < BN; r += 1024){
    int idx = r*Dd + d;
    float v = agg[idx]*sc + sh;
    v = fmaxf(v, 0.f);
    v *= e;
    agg[idx] = v;
    s += v; q += v*v;
  }
  ssum[threadIdx.x] = s; ssq[threadIdx.x] = q;
  __syncthreads();
  if (threadIdx.x < 64){
    #pragma unroll
    for (int k = 1; k < 4; k++){ s += ssum[threadIdx.x + 64*k]; q += ssq[threadIdx.x + 64*k]; }
    atomicAdd(&gsum2[d], s);
    atomicAdd(&gsq2[d], q);
  }
}

// ---------------- S9: bn2 + relu + Linear(D,1) head ----------------
__global__ __launch_bounds__(256) void k_out(const float* __restrict__ h2,
    const float* __restrict__ scale2, const float* __restrict__ shift2,
    const float* __restrict__ outW, const float* __restrict__ outb,
    float* __restrict__ out){
  int row  = blockIdx.x*4 + (threadIdx.x>>6);
  int lane = threadIdx.x & 63;
  float v = h2[row*Dd + lane]*scale2[lane] + shift2[lane];
  v = fmaxf(v, 0.f) * outW[lane];
  float s = wave_sum(v);
  if (lane == 0) out[row] = s + outb[0];
}

extern "C" void kernel_launch(void* const* d_in, const int* in_sizes, int n_in,
                              void* d_out, int out_size, void* d_ws, size_t ws_size,
                              hipStream_t stream){
  const float* data  = (const float*)d_in[0];
  // d_in[1] = org_edge_index — unused by the reference computation
  const float* embed = (const float*)d_in[2];
  const float* W_lin = (const float*)d_in[3];
  const float* att_i = (const float*)d_in[4];
  const float* att_j = (const float*)d_in[5];
  const float* aem_i = (const float*)d_in[6];
  const float* aem_j = (const float*)d_in[7];
  const float* bias  = (const float*)d_in[8];
  const float* g1    = (const float*)d_in[9];
  const float* b1    = (const float*)d_in[10];
  const float* g2    = (const float*)d_in[11];
  const float* b2    = (const float*)d_in[12];
  const float* outW  = (const float*)d_in[13];
  const float* outb  = (const float*)d_in[14];
  float* out = (float*)d_out;

  float* ws    = (float*)d_ws;
  float* g     = ws;                       // 4,194,304 f32  (16 MB)
  float* agg   = ws + 4194304;             // 4,194,304 f32  (16 MB, reused as h2)
  float* enorm = ws + 8388608;             // 32,768
  float* s_i   = enorm + 32768;            // 65,536
  float* s_j   = s_i + 65536;              // 65,536
  int*   topk  = (int*)(s_j + 65536);      // 10,240 int
  float* st    = (float*)(topk + Nn*Kk);   // stats block
  float* sum1 = st,      *sq1 = st+64,  *sum2 = st+128, *sq2 = st+192;
  float* sc1  = st+256,  *sh1 = st+320, *sc2  = st+384, *sh2 = st+448;

  hipMemsetAsync(st, 0, 256*sizeof(float), stream);            // zero stat accumulators
  k_enorm<<<Nn/4, 256, 0, stream>>>(embed, enorm);
  k_topk <<<Nn/4, 256, 0, stream>>>(enorm, topk);
  k_lin  <<<BN/64, 256, 0, stream>>>(data, W_lin, embed, att_i, att_j, aem_i, aem_j,
                                     g, s_i, s_j);
  k_agg  <<<BN/4, 256, 0, stream>>>(g, s_i, s_j, topk, bias, agg);
  k_stats<<<256,  256, 0, stream>>>(agg, sum1, sq1);
  k_fin  <<<1, 64, 0, stream>>>(sum1, sq1, g1, b1, sc1, sh1);
  k_h2   <<<256,  256, 0, stream>>>(agg, embed, sc1, sh1, sum2, sq2);
  k_fin  <<<1, 64, 0, stream>>>(sum2, sq2, g2, b2, sc2, sh2);
  k_out  <<<BN/4, 256, 0, stream>>>(agg, sc2, sh2, outW, outb, out);
}